// Round 2
// baseline (736.654 us; speedup 1.0000x reference)
//
#include <hip/hip_runtime.h>

// Murray single-area 2-unit RNN scan.
// B=8192 independent sequential chains of T*spb=8000 sub-steps -> latency-bound.
// One thread per batch element (ILP=2 from the two units). 64-thread blocks so
// the 128 waves spread across CUs.
//
// R2 fix: the act==0 singularity guard must be a WINDOW, not exact-zero.
// fma cancellation can yield tiny nonzero x where hw exp2(x)==1.0 exactly ->
// d=0 -> rcp=inf -> NaN cascade. Guard |x| < 1e-5 (limit value 1/C; rel err
// of the limit there is ~3.5e-6, far below the 29.28 abs threshold).

#define AF    270.0f
#define BF    108.0f
#define CF    0.154f
#define DTF   0.001f
#define I0F   0.334f
#define TAUF  0.06f
#define GAMF  0.641f
#define LOG2EF 1.44269504088896340736f
#define LN2F   0.69314718055994530942f

#if __has_builtin(__builtin_amdgcn_exp2f)
#define EXP2F(x) __builtin_amdgcn_exp2f(x)
#else
#define EXP2F(x) exp2f(x)
#endif

#if __has_builtin(__builtin_amdgcn_rcpf)
#define RCPF(x) __builtin_amdgcn_rcpf(x)
#else
#define RCPF(x) (1.0f / (x))
#endif

struct Consts {
  // x_j = -C*log2e * act_j, act_j = A*(s0*J0j + s1*J1j + I0 + in_j) - B
  float X00, X10, X01, X11;  // coeffs of s0/s1 in x0/x1 (A and -C*log2e folded in)
  float P, Q;                // x contribution of input: xq_j = P*in_j + Q
  float K1;                  // 1 - sub_dt/TAU
  float K2C;                 // sub_dt*GAMMA*INVC (applied to (1-s)*x/denom)
  float INVC;                // rate = INVC * (x * rcp(1-exp2(x))) ; INVC = -ln2/C
};

// One sub-step for both units. r20/r21 hold the (scaled) rate of THIS sub-step.
__device__ __forceinline__ void substep(const Consts& c, float xq0, float xq1,
                                        float& s0, float& s1, float& r20, float& r21) {
  float x0 = fmaf(c.X00, s0, fmaf(c.X10, s1, xq0));
  float x1 = fmaf(c.X01, s0, fmaf(c.X11, s1, xq1));
  float e0 = EXP2F(x0);
  float e1 = EXP2F(x1);
  float d0 = 1.0f - e0;
  float d1 = 1.0f - e1;
  float t0 = x0 * RCPF(d0);
  float t1 = x1 * RCPF(d1);
  // near act==0: rate -> 1/C  <=>  scaled r2 -> -log2e.
  // Window guard (NOT exact ==0): for |x|<1e-5 hw exp2 may round to 1.0
  // (d==0 -> inf); the limit value is accurate to ~3.5e-6 relative there.
  r20 = (__builtin_fabsf(x0) < 1e-5f) ? -LOG2EF : t0;
  r21 = (__builtin_fabsf(x1) < 1e-5f) ? -LOG2EF : t1;
  float u0 = fmaf(-s0, r20, r20);   // (1-s)*r2
  float u1 = fmaf(-s1, r21, r21);
  s0 = fmaf(c.K2C, u0, c.K1 * s0);
  s1 = fmaf(c.K2C, u1, c.K1 * s1);
}

// One bin: spb sub-steps; outputs rate of the LAST sub-step (pre-update state).
template <int SPB>
__device__ __forceinline__ void bin(const Consts& c, int spb, float in0, float in1,
                                    float& s0, float& s1, float& rt0, float& rt1) {
  float xq0 = fmaf(c.P, in0, c.Q);
  float xq1 = fmaf(c.P, in1, c.Q);
  float r20 = -LOG2EF, r21 = -LOG2EF;
  if (SPB > 0) {
#pragma unroll
    for (int k = 0; k < SPB; ++k) substep(c, xq0, xq1, s0, s1, r20, r21);
  } else {
    for (int k = 0; k < spb; ++k) substep(c, xq0, xq1, s0, s1, r20, r21);
  }
  rt0 = c.INVC * r20;
  rt1 = c.INVC * r21;
}

template <int SPB>
__device__ __forceinline__ void run_loop(const Consts& c, int spb, int T,
                                         const float* __restrict__ ip,
                                         float* __restrict__ sp, float* __restrict__ rp,
                                         float& s0, float& s1) {
  const int nch = T / 8;  // 8 bins per chunk = 64 B per thread = one cache line
  const float4* ip4 = (const float4*)ip;
  float4* sp4 = (float4*)sp;
  float4* rp4 = (float4*)rp;
  float4 bufA[4], bufB[4];
  if (nch > 0) {
#pragma unroll
    for (int i = 0; i < 4; ++i) { bufA[i] = ip4[i]; bufB[i] = bufA[i]; }
  }
  for (int ch = 0; ch < nch; ++ch) {
    if (ch + 1 < nch) {
#pragma unroll
      for (int i = 0; i < 4; ++i) bufB[i] = ip4[(ch + 1) * 4 + i];
    }
#pragma unroll
    for (int p = 0; p < 4; ++p) {  // 2 bins per float4
      float4 v = bufA[p];
      float rt0a, rt1a, rt0b, rt1b;
      bin<SPB>(c, spb, v.x, v.y, s0, s1, rt0a, rt1a);
      float s0a = s0, s1a = s1;
      bin<SPB>(c, spb, v.z, v.w, s0, s1, rt0b, rt1b);
      float4 st; st.x = s0a; st.y = s1a; st.z = s0; st.w = s1;
      float4 rt; rt.x = rt0a; rt.y = rt1a; rt.z = rt0b; rt.w = rt1b;
      sp4[ch * 4 + p] = st;
      rp4[ch * 4 + p] = rt;
    }
#pragma unroll
    for (int i = 0; i < 4; ++i) bufA[i] = bufB[i];
  }
  // tail (T % 8)
  for (int t = nch * 8; t < T; ++t) {
    float in0 = ip[2 * t], in1 = ip[2 * t + 1];
    float rt0, rt1;
    bin<SPB>(c, spb, in0, in1, s0, s1, rt0, rt1);
    sp[2 * t] = s0; sp[2 * t + 1] = s1;
    rp[2 * t] = rt0; rp[2 * t + 1] = rt1;
  }
}

__global__ __launch_bounds__(64, 1)
void murray_kernel(const float* __restrict__ inp, const float* __restrict__ h0,
                   const float* __restrict__ Jm, const int* __restrict__ spb_p,
                   float* __restrict__ out, int B, int T) {
  const int b = blockIdx.x * 64 + threadIdx.x;
  if (b >= B) return;
  const int spb = *spb_p;

  const float J00 = Jm[0], J01 = Jm[1], J10 = Jm[2], J11 = Jm[3];
  const float sub_dt = DTF / (float)spb;
  const float NC = -CF * LOG2EF;  // fold exp -> exp2

  Consts c;
  c.X00 = NC * AF * J00; c.X10 = NC * AF * J10;
  c.X01 = NC * AF * J01; c.X11 = NC * AF * J11;
  c.P   = NC * AF;
  c.Q   = NC * fmaf(AF, I0F, -BF);
  c.K1  = 1.0f - sub_dt / TAUF;
  c.INVC = -LN2F / CF;
  c.K2C = sub_dt * GAMF * c.INVC;

  float s0 = h0[2 * b], s1 = h0[2 * b + 1];

  const size_t row = (size_t)(2 * T);
  const float* ip = inp + (size_t)b * row;
  float* sp = out + (size_t)b * row;                       // states [B,T,2]
  float* rp = out + (size_t)B * row + (size_t)b * row;     // rates  [B,T,2]
  float* fp = out + (size_t)B * row * 2 + (size_t)b * 2;   // final  [1,B,2]

  if (spb == 4) {
    run_loop<4>(c, spb, T, ip, sp, rp, s0, s1);
  } else {
    run_loop<0>(c, spb, T, ip, sp, rp, s0, s1);
  }

  fp[0] = s0;
  fp[1] = s1;
}

extern "C" void kernel_launch(void* const* d_in, const int* in_sizes, int n_in,
                              void* d_out, int out_size, void* d_ws, size_t ws_size,
                              hipStream_t stream) {
  const float* inp = (const float*)d_in[0];
  const float* h0  = (const float*)d_in[1];
  const float* J   = (const float*)d_in[2];
  const int* spb   = (const int*)d_in[3];
  float* out = (float*)d_out;

  const int B = in_sizes[1] / 2;            // h0 is [1,B,2]
  const int T = in_sizes[0] / (2 * B);      // input is [B,T,2]
  const int blocks = (B + 63) / 64;

  murray_kernel<<<blocks, 64, 0, stream>>>(inp, h0, J, spb, out, B, T);
}